// Round 1
// baseline (370.202 us; speedup 1.0000x reference)
//
#include <hip/hip_runtime.h>

// y[b,c,m] = sum_{a<4, l<16} h[b,c,a,m,l] * x[b,a,m-l]   (m-l valid in [0,NT))
// Shapes: x[32,1,4,2048] f32, h[32,1,16,1,4,2063,16] f32, y[32,1,16,2063] f32.
// Memory-bound on h (270 MB single-pass stream). Floor ~44 us at 6.3 TB/s.

#define NTT 2048
#define LL  16
#define TT  2063
#define NC  16   // RXA
#define NA  4    // TXA
#define BM  256  // m per block
#define MT  ((TT + BM - 1) / BM)   // 9 m-tiles

__global__ __launch_bounds__(BM) void atc_kernel(
    const float* __restrict__ x,   // [B,1,NA,NTT]
    const float* __restrict__ h,   // [B,1,NC,1,NA,TT,LL]
    float* __restrict__ y)         // [B,1,NC,TT]
{
    // x windows for this block's m-range [m0-15, m0+BM-1]: NA * (BM+15) floats
    __shared__ float xs[NA][BM + LL];  // padded to 272 cols

    const int bid = blockIdx.x;
    const int mt  = bid % MT;
    const int c   = (bid / MT) % NC;
    const int b   = bid / (MT * NC);
    const int m0  = mt * BM;
    const int tid = threadIdx.x;

    // Stage x windows into LDS (zero-fill outside [0, NTT))
    const int WIN = BM + LL - 1;  // 271
    for (int i = tid; i < NA * WIN; i += BM) {
        const int a = i / WIN;
        const int j = i - a * WIN;
        const int tg = m0 - (LL - 1) + j;   // global time index
        float v = 0.0f;
        if (tg >= 0 && tg < NTT) v = x[(b * NA + a) * NTT + tg];
        xs[a][j] = v;
    }
    __syncthreads();

    const int m = m0 + tid;
    if (m < TT) {
        float acc = 0.0f;
        #pragma unroll
        for (int a = 0; a < NA; ++a) {
            const float4* hp = reinterpret_cast<const float4*>(
                h + ((size_t)((b * NC + c) * NA + a) * TT + m) * LL);
            const float4 h0 = hp[0];
            const float4 h1 = hp[1];
            const float4 h2 = hp[2];
            const float4 h3 = hp[3];
            // xs[a][tid + 15 - l] == x[b, a, m - l]
            const float* xw = &xs[a][tid];
            acc += h0.x * xw[15] + h0.y * xw[14] + h0.z * xw[13] + h0.w * xw[12];
            acc += h1.x * xw[11] + h1.y * xw[10] + h1.z * xw[ 9] + h1.w * xw[ 8];
            acc += h2.x * xw[ 7] + h2.y * xw[ 6] + h2.z * xw[ 5] + h2.w * xw[ 4];
            acc += h3.x * xw[ 3] + h3.y * xw[ 2] + h3.z * xw[ 1] + h3.w * xw[ 0];
        }
        y[(size_t)(b * NC + c) * TT + m] = acc;
    }
}

extern "C" void kernel_launch(void* const* d_in, const int* in_sizes, int n_in,
                              void* d_out, int out_size, void* d_ws, size_t ws_size,
                              hipStream_t stream) {
    const float* x = (const float*)d_in[0];
    const float* h = (const float*)d_in[1];
    // d_in[2] (g) unused: toeplitz indices are computed analytically.
    float* y = (float*)d_out;

    const int nblocks = 32 * NC * MT;  // 4608
    atc_kernel<<<nblocks, BM, 0, stream>>>(x, h, y);
}